// Round 7
// baseline (94.426 us; speedup 1.0000x reference)
//
#include <hip/hip_runtime.h>

// LinearAttention fused pipeline, MI355X gfx950. Round 7.
// Round-6 structure with the barrier race fixed: __syncthreads() (full
// IR-level fence) instead of raw s_barrier+asm, one sync per pipeline step.
// k_init:      w_qkv->wh f16, w_out->wouth f16, zero kv/den
// k_transpose: x[b][c][n] f32 -> xh[b][n][c] f16
// k_kv:        double-buffered BK=32 pipeline; k'=elu1(Wk.x), v=Wv.x;
//              kv/den in-register -> atomics. 72KB LDS, 2 blocks/CU.
// k_fused2:    16-step pipeline: Q=elu1(Wq.x)*s*1024 -> swizzled Q-LDS ->
//              out=wouth.Q -> fused LayerNorm.

#define NB 16
#define NC 256
#define NN 4096
#define LN_EPS 1e-5f
#define IOSCALE (1.0f/1024.0f)

typedef _Float16 f16;
typedef _Float16 f16x8 __attribute__((ext_vector_type(8)));
typedef _Float16 f16x4v __attribute__((ext_vector_type(4)));
typedef float f32x4 __attribute__((ext_vector_type(4)));

typedef __attribute__((address_space(1))) const unsigned int* as1cu32;
typedef __attribute__((address_space(3))) unsigned int* as3u32;

__device__ __forceinline__ void gload16(const void* g, void* l) {
  __builtin_amdgcn_global_load_lds((as1cu32)g, (as3u32)l, 16, 0, 0);
}
__device__ __forceinline__ float elu1(float x) {
  return x > 0.f ? x + 1.f : __expf(x);
}
#define MFMA16 __builtin_amdgcn_mfma_f32_16x16x32_f16

__global__ __launch_bounds__(256) void k_init(const float* __restrict__ wqkv,
                                              const float* __restrict__ wout,
                                              f16* __restrict__ wh,
                                              f16* __restrict__ wouth,
                                              float* __restrict__ kvden) {
  int i = blockIdx.x * 256 + threadIdx.x;
  wh[i] = (f16)wqkv[i];
  if (i < 65536) wouth[i] = (f16)wout[i];
  if (i < 8192) kvden[i] = 0.f;
}

// x[b][c][n] f32 -> xh[b][n][c] f16. 64x64 tiles via padded LDS.
__global__ __launch_bounds__(256) void k_transpose(const float* __restrict__ x,
                                                   f16* __restrict__ xh) {
  __shared__ float t[64 * 65];
  const int b = blockIdx.z, c0 = blockIdx.y * 64, n0 = blockIdx.x * 64;
  const int tid = threadIdx.x;
#pragma unroll
  for (int i = 0; i < 4; ++i) {
    int lin = tid + i * 256;
    int r = lin >> 4;
    int cg = lin & 15;
    const float4 v = *reinterpret_cast<const float4*>(
        &x[((size_t)(b * NC + c0 + r)) * NN + n0 + cg * 4]);
    t[r * 65 + cg * 4 + 0] = v.x;
    t[r * 65 + cg * 4 + 1] = v.y;
    t[r * 65 + cg * 4 + 2] = v.z;
    t[r * 65 + cg * 4 + 3] = v.w;
  }
  __syncthreads();
#pragma unroll
  for (int i = 0; i < 4; ++i) {
    int lin = tid + i * 256;
    int nr = lin >> 4;
    int cg = lin & 15;
    f16x4v h;
    h[0] = (f16)t[(cg * 4 + 0) * 65 + nr];
    h[1] = (f16)t[(cg * 4 + 1) * 65 + nr];
    h[2] = (f16)t[(cg * 4 + 2) * 65 + nr];
    h[3] = (f16)t[(cg * 4 + 3) * 65 + nr];
    *reinterpret_cast<f16x4v*>(&xh[((size_t)(b * NN + n0 + nr)) * NC + c0 + cg * 4]) = h;
  }
}

// kv/den. Block: 64n x all 256 ch (k&v). 512 thr = 8 waves = 2 ng x 4 cg.
// LDS [R][32]-f16 chunks, 16B-unit XOR swizzle (unit ^ (row&3)).
__global__ __launch_bounds__(512, 4) void k_kv(const f16* __restrict__ xh,
                                               const f16* __restrict__ wh,
                                               float* __restrict__ kv,
                                               float* __restrict__ den) {
  __shared__ __align__(16) f16 Xc[2][64 * 32];    // 8 KB
  __shared__ __align__(16) f16 Bt[2][512 * 32];   // 64 KB (k rows 0..255, v 256..511)
  const int b = blockIdx.y;
  const int n0 = blockIdx.x * 64;
  const int tid = threadIdx.x;
  const int lane = tid & 63;
  const int wv = tid >> 6;
  const int ng = wv >> 2, cg = wv & 3;
  const int l15 = lane & 15, lg = lane >> 4;
  const int srow = lane >> 2;                       // staging row-in-16
  const int scol = (((lane & 3) ^ (srow & 3)) * 8); // pre-swizzled src col (halves)
  const int xu = ((lg ^ (l15 & 3)) << 3);           // swizzled read col (halves)

  f32x4 kacc[2][4] = {};
  f32x4 vacc[2][4] = {};

  // prologue: stage chunk 0 into buf 0
#pragma unroll
  for (int i = 0; i < 4; ++i) {
    const int inst = wv * 4 + i;
    gload16(wh + (size_t)(256 + inst * 16 + srow) * NC + scol, &Bt[0][inst * 512]);
  }
  if (wv < 4)
    gload16(xh + ((size_t)(b * NN + n0 + wv * 16 + srow)) * NC + scol, &Xc[0][wv * 512]);
  __syncthreads();

  for (int s = 0; s < 8; ++s) {
    const int cb = s & 1, nb = (s + 1) & 1;
    if (s < 7) {
      const int c0 = (s + 1) * 32;
#pragma unroll
      for (int i = 0; i < 4; ++i) {
        const int inst = wv * 4 + i;
        gload16(wh + (size_t)(256 + inst * 16 + srow) * NC + c0 + scol, &Bt[nb][inst * 512]);
      }
      if (wv < 4)
        gload16(xh + ((size_t)(b * NN + n0 + wv * 16 + srow)) * NC + c0 + scol, &Xc[nb][wv * 512]);
    }
    const f16x8 a0 = *(const f16x8*)(&Xc[cb][(ng * 32 + l15) * 32 + xu]);
    const f16x8 a1 = *(const f16x8*)(&Xc[cb][(ng * 32 + 16 + l15) * 32 + xu]);
#pragma unroll
    for (int f = 0; f < 4; ++f) {
      const f16x8 bk = *(const f16x8*)(&Bt[cb][(cg * 64 + f * 16 + l15) * 32 + xu]);
      kacc[0][f] = MFMA16(a0, bk, kacc[0][f], 0, 0, 0);
      kacc[1][f] = MFMA16(a1, bk, kacc[1][f], 0, 0, 0);
      const f16x8 bv = *(const f16x8*)(&Bt[cb][(256 + cg * 64 + f * 16 + l15) * 32 + xu]);
      vacc[0][f] = MFMA16(a0, bv, vacc[0][f], 0, 0, 0);
      vacc[1][f] = MFMA16(a1, bv, vacc[1][f], 0, 0, 0);
    }
    if (s < 7) __syncthreads();
  }

  float pkv[4] = {0.f, 0.f, 0.f, 0.f}, pden[4] = {0.f, 0.f, 0.f, 0.f};
#pragma unroll
  for (int f = 0; f < 4; ++f)
#pragma unroll
    for (int m = 0; m < 2; ++m)
#pragma unroll
      for (int j = 0; j < 4; ++j) {
        const float kk = elu1(kacc[m][f][j]);
        pkv[f] += kk * vacc[m][f][j];
        pden[f] += kk;
      }
#pragma unroll
  for (int f = 0; f < 4; ++f) {
    pkv[f] += __shfl_xor(pkv[f], 16, 64);
    pkv[f] += __shfl_xor(pkv[f], 32, 64);
    pden[f] += __shfl_xor(pden[f], 16, 64);
    pden[f] += __shfl_xor(pden[f], 32, 64);
  }
  if (lane < 16) {
#pragma unroll
    for (int f = 0; f < 4; ++f) {
      const int c = cg * 64 + f * 16 + lane;
      atomicAdd(&kv[b * NC + c], pkv[f]);
      atomicAdd(&den[b * NC + c], pden[f]);
    }
  }
}

// Fused GEMM1(q)+scale -> Q(swizzled LDS) -> GEMM2 -> LN. 512 thr = 8 waves
// = 4 cg x 2 ng. 16 pipelined steps (8 Wq + 8 wouth chunks).
__global__ __launch_bounds__(512, 4) void k_fused2(const f16* __restrict__ xh,
                                                   const f16* __restrict__ wh,
                                                   const f16* __restrict__ wouth,
                                                   const float* __restrict__ kv,
                                                   const float* __restrict__ den,
                                                   const float* __restrict__ gamma,
                                                   const float* __restrict__ beta,
                                                   float* __restrict__ out) {
  __shared__ __align__(16) f16 Xc[2][64 * 32];    // 8 KB (overlaid by LN scratch later)
  __shared__ __align__(16) f16 Wt[2][256 * 32];   // 32 KB
  __shared__ __align__(16) f16 Q[64 * 256];       // 32 KB, 16B-unit XOR swizzle
  const int b = blockIdx.y;
  const int n0 = blockIdx.x * 64;
  const int tid = threadIdx.x;
  const int lane = tid & 63;
  const int wv = tid >> 6;
  const int cg = wv >> 1, ng = wv & 1;
  const int l15 = lane & 15, lg = lane >> 4;
  const int srow = lane >> 2;
  const int scol = (((lane & 3) ^ (srow & 3)) * 8);
  const int xu = ((lg ^ (l15 & 3)) << 3);

  // per-lane scale s*1024 for the 16 q-channels this lane will write
  float sreg[4][4];
#pragma unroll
  for (int m = 0; m < 4; ++m)
#pragma unroll
    for (int j = 0; j < 4; ++j) {
      const int c = cg * 64 + m * 16 + lg * 4 + j;
      sreg[m][j] = kv[b * NC + c] / fmaxf(den[b * NC + c], 1e-6f) * 1024.0f;
    }

  // prologue: stage Wq chunk0 + x chunk0
#pragma unroll
  for (int i = 0; i < 2; ++i) {
    const int inst = wv * 2 + i;
    gload16(wh + (size_t)(inst * 16 + srow) * NC + scol, &Wt[0][inst * 512]);
  }
  if (wv < 4)
    gload16(xh + ((size_t)(b * NN + n0 + wv * 16 + srow)) * NC + scol, &Xc[0][wv * 512]);
  __syncthreads();

  f32x4 acc[4][2] = {};
  for (int s = 0; s < 8; ++s) {
    const int cb = s & 1, nb = (s + 1) & 1;
    if (s < 7) {
      const int c0 = (s + 1) * 32;
#pragma unroll
      for (int i = 0; i < 2; ++i) {
        const int inst = wv * 2 + i;
        gload16(wh + (size_t)(inst * 16 + srow) * NC + c0 + scol, &Wt[nb][inst * 512]);
      }
      if (wv < 4)
        gload16(xh + ((size_t)(b * NN + n0 + wv * 16 + srow)) * NC + c0 + scol, &Xc[nb][wv * 512]);
    } else {
      // stage GEMM2 chunk 0 (wouth) into the other buffer
#pragma unroll
      for (int i = 0; i < 2; ++i) {
        const int inst = wv * 2 + i;
        gload16(wouth + (size_t)(inst * 16 + srow) * NC + scol, &Wt[nb][inst * 512]);
      }
    }
    f16x8 a[4], bx[2];
#pragma unroll
    for (int m = 0; m < 4; ++m)
      a[m] = *(const f16x8*)(&Wt[cb][(cg * 64 + m * 16 + l15) * 32 + xu]);
#pragma unroll
    for (int f = 0; f < 2; ++f)
      bx[f] = *(const f16x8*)(&Xc[cb][(ng * 32 + f * 16 + l15) * 32 + xu]);
#pragma unroll
    for (int m = 0; m < 4; ++m)
#pragma unroll
      for (int f = 0; f < 2; ++f)
        acc[m][f] = MFMA16(a[m], bx[f], acc[m][f], 0, 0, 0);
    if (s < 7) __syncthreads();
  }

  // Q publish: Q[n][c] = elu1(q)*s*1024, 16B-unit swizzled by (n&7)
#pragma unroll
  for (int m = 0; m < 4; ++m) {
#pragma unroll
    for (int f = 0; f < 2; ++f) {
      const int n = ng * 32 + f * 16 + l15;
      const int ch = cg * 64 + m * 16 + lg * 4;
      const int u = ch >> 3;
      f16x4v h;
#pragma unroll
      for (int j = 0; j < 4; ++j)
        h[j] = (f16)(elu1(acc[m][f][j]) * sreg[m][j]);
      *reinterpret_cast<f16x4v*>(&Q[n * 256 + ((u ^ (n & 7)) << 3) + (ch & 7)]) = h;
    }
  }
  __syncthreads();   // publishes Q; also drains wouth chunk0 DMA

  f32x4 acc2[4][2] = {};
  for (int s = 0; s < 8; ++s) {
    const int cb = s & 1, nb = (s + 1) & 1;
    if (s < 7) {
      const int c0 = (s + 1) * 32;
#pragma unroll
      for (int i = 0; i < 2; ++i) {
        const int inst = wv * 2 + i;
        gload16(wouth + (size_t)(inst * 16 + srow) * NC + c0 + scol, &Wt[nb][inst * 512]);
      }
    }
    f16x8 a[4], bq[2];
#pragma unroll
    for (int m = 0; m < 4; ++m)
      a[m] = *(const f16x8*)(&Wt[cb][(cg * 64 + m * 16 + l15) * 32 + xu]);
#pragma unroll
    for (int f = 0; f < 2; ++f) {
      const int n = ng * 32 + f * 16 + l15;
      const int U = s * 4 + lg;
      bq[f] = *(const f16x8*)(&Q[n * 256 + ((U ^ (n & 7)) << 3)]);
    }
#pragma unroll
    for (int m = 0; m < 4; ++m)
#pragma unroll
      for (int f = 0; f < 2; ++f)
        acc2[m][f] = MFMA16(a[m], bq[f], acc2[m][f], 0, 0, 0);
    if (s < 7) __syncthreads();
  }

  // LayerNorm over o (256) per column n; scratch overlays dead Xc
  float* red1 = (float*)(&Xc[0][0]);   // [4][64]
  float* red2 = red1 + 256;
  float* smu = red2 + 256;             // [64]
  float* srs = smu + 64;
  float s1[2] = {0, 0}, s2[2] = {0, 0};
#pragma unroll
  for (int f = 0; f < 2; ++f)
#pragma unroll
    for (int m = 0; m < 4; ++m)
#pragma unroll
      for (int j = 0; j < 4; ++j) {
        const float v = acc2[m][f][j];
        s1[f] += v;
        s2[f] += v * v;
      }
#pragma unroll
  for (int f = 0; f < 2; ++f) {
    s1[f] += __shfl_xor(s1[f], 16, 64);
    s1[f] += __shfl_xor(s1[f], 32, 64);
    s2[f] += __shfl_xor(s2[f], 16, 64);
    s2[f] += __shfl_xor(s2[f], 32, 64);
  }
  __syncthreads();   // retire last Wt/Q reads before overlaying Xc scratch
  if (lane < 16) {
#pragma unroll
    for (int f = 0; f < 2; ++f) {
      red1[cg * 64 + ng * 32 + f * 16 + lane] = s1[f];
      red2[cg * 64 + ng * 32 + f * 16 + lane] = s2[f];
    }
  }
  __syncthreads();
  if (tid < 64) {
    const float a1 = red1[tid] + red1[64 + tid] + red1[128 + tid] + red1[192 + tid];
    const float a2 = red2[tid] + red2[64 + tid] + red2[128 + tid] + red2[192 + tid];
    const float mu = a1 * (IOSCALE / 256.f);
    const float e2 = a2 * (IOSCALE * IOSCALE / 256.f);
    smu[tid] = mu;
    srs[tid] = rsqrtf(e2 - mu * mu + LN_EPS);
  }
  __syncthreads();
#pragma unroll
  for (int m = 0; m < 4; ++m) {
    const int ob = cg * 64 + m * 16 + lg * 4;
#pragma unroll
    for (int j = 0; j < 4; ++j) {
      const int o = ob + j;
      const float g = gamma[o], be = beta[o];
#pragma unroll
      for (int f = 0; f < 2; ++f) {
        const int col = ng * 32 + f * 16 + l15;
        const float v = acc2[m][f][j] * IOSCALE;
        out[((size_t)(b * NC + o)) * NN + n0 + col] = (v - smu[col]) * srs[col] * g + be;
      }
    }
  }
}

extern "C" void kernel_launch(void* const* d_in, const int* in_sizes, int n_in,
                              void* d_out, int out_size, void* d_ws, size_t ws_size,
                              hipStream_t stream) {
  const float* x = (const float*)d_in[0];
  const float* w_qkv = (const float*)d_in[1];
  const float* w_out = (const float*)d_in[2];
  const float* ln_g = (const float*)d_in[3];
  const float* ln_b = (const float*)d_in[4];
  float* out = (float*)d_out;

  char* wsb = (char*)d_ws;
  const size_t OFF_WH = 0;                        // 768*256*2 = 393216
  const size_t OFF_WOUTH = 393216;                // 256*256*2 = 131072
  const size_t OFF_XH = OFF_WOUTH + 131072;       // 32 MiB
  const size_t OFF_KV = OFF_XH + 33554432;        // 16 KiB
  const size_t OFF_DEN = OFF_KV + 16384;          // 16 KiB

  f16* wh = (f16*)(wsb + OFF_WH);
  f16* wouth = (f16*)(wsb + OFF_WOUTH);
  f16* xh = (f16*)(wsb + OFF_XH);
  float* kv = (float*)(wsb + OFF_KV);
  float* den = (float*)(wsb + OFF_DEN);

  k_init<<<768, 256, 0, stream>>>(w_qkv, w_out, wh, wouth, kv);
  k_transpose<<<dim3(64, 4, 16), 256, 0, stream>>>(x, xh);
  k_kv<<<dim3(64, 16), 512, 0, stream>>>(xh, wh, kv, den);
  k_fused2<<<dim3(64, 16), 512, 0, stream>>>(xh, wh, wouth, kv, den, ln_g, ln_b, out);
}